// Round 10
// baseline (203.488 us; speedup 1.0000x reference)
//
#include <hip/hip_runtime.h>

typedef __bf16 bf16;
typedef __bf16 bf16x4 __attribute__((ext_vector_type(4)));
typedef __bf16 bf16x8 __attribute__((ext_vector_type(8)));
typedef float  f32x4  __attribute__((ext_vector_type(4)));
typedef float  f32x16 __attribute__((ext_vector_type(16)));
typedef unsigned int u32x4v __attribute__((ext_vector_type(4)));

#define NB   4
#define SEQ  2048
#define DM   1024
#define NH   16
#define HD   64
#define BHN  (NB*NH)       // 64
#define MTOT (NB*SEQ)      // 8192
#define ELEMS ((size_t)MTOT*DM)  // 8388608
#define WELEMS (DM*DM)     // 1048576
#define QSCALE 0.18033688011112042f   // 0.125 * log2(e): scores in log2 units

__device__ __forceinline__ void gload16(void* lds, const void* g) {
  __builtin_amdgcn_global_load_lds(
      (const __attribute__((address_space(1))) void*)g,
      (__attribute__((address_space(3))) void*)lds, 16, 0, 0);
}

__device__ __forceinline__ f32x4 mfma16(bf16x8 a, bf16x8 b, f32x4 c) {
  return __builtin_amdgcn_mfma_f32_16x16x32_bf16(a, b, c, 0, 0, 0);
}
__device__ __forceinline__ f32x16 mfma32(bf16x8 a, bf16x8 b, f32x16 c) {
  return __builtin_amdgcn_mfma_f32_32x32x16_bf16(a, b, c, 0, 0, 0);
}
__device__ __forceinline__ unsigned cvtpk(float lo, float hi) {
  unsigned r;
  asm("v_cvt_pk_bf16_f32 %0, %1, %2" : "=v"(r) : "v"(lo), "v"(hi));
  return r;
}
__device__ __forceinline__ float exp2a(float x) {   // D = 2^x
  float r;
  asm("v_exp_f32 %0, %1" : "=v"(r) : "v"(x));
  return r;
}

// fp32 -> bf16 conversion: y=0..3 -> W_y, y=4 -> x
__global__ __launch_bounds__(256) void cvt_all(
    const float* __restrict__ x, bf16* __restrict__ xb,
    const float* __restrict__ w0, const float* __restrict__ w1,
    const float* __restrict__ w2, const float* __restrict__ w3,
    bf16* __restrict__ wb)
{
  int y = blockIdx.y;
  const float* src; bf16* dst; int nblk;
  if (y < 4) {
    src = (y == 0) ? w0 : (y == 1) ? w1 : (y == 2) ? w2 : w3;
    dst = wb + (size_t)y * WELEMS;
    nblk = WELEMS / 1024;
  } else {
    src = x; dst = xb; nblk = (int)(ELEMS / 1024);
  }
  if (blockIdx.x >= nblk) return;
  int i = blockIdx.x * 1024 + threadIdx.x * 4;
  f32x4 v = *(const f32x4*)(src + i);
  bf16x4 o;
#pragma unroll
  for (int j = 0; j < 4; j++) o[j] = (bf16)v[j];
  *(bf16x4*)(dst + i) = o;
}

// ---- shared GEMM core (m97 structure): acc[4][4] for a 128x128 tile
#define GEMM_CORE(A_, W_)                                                      \
  __shared__ __align__(16) bf16 lds_a[128*32];                                 \
  __shared__ __align__(16) bf16 lds_b[128*32];                                 \
  const int K = 1024;                                                          \
  int tid = threadIdx.x, wid = tid >> 6, lane = tid & 63;                      \
  int m0 = blockIdx.y * 128, n0 = blockIdx.x * 128;                            \
  int wr = wid >> 1, wc = wid & 1;                                             \
  int c15 = lane & 15, hi = lane >> 4;                                         \
  int srow = lane >> 2, scol = (lane & 3) * 8;                                 \
  const bf16* gA = (A_) + (m0 + wid*32 + srow) * K + scol;                     \
  const bf16* gB = (W_) + (n0 + wid*32 + srow) * K + scol;                     \
  bf16* la = lds_a + wid*1024;                                                 \
  bf16* lb = lds_b + wid*1024;                                                 \
  f32x4 acc[4][4] = {};                                                        \
  for (int k0 = 0; k0 < K; k0 += 32) {                                         \
    __syncthreads();                                                           \
    gload16(la,       gA + k0);                                                \
    gload16(la + 512, gA + 16*K + k0);                                         \
    gload16(lb,       gB + k0);                                                \
    gload16(lb + 512, gB + 16*K + k0);                                         \
    __syncthreads();                                                           \
    bf16x8 af[4], bfr[4];                                                      \
    _Pragma("unroll")                                                          \
    for (int i = 0; i < 4; i++)                                                \
      af[i]  = *(const bf16x8*)(lds_a + (wr*64 + i*16 + c15)*32 + hi*8);       \
    _Pragma("unroll")                                                          \
    for (int i = 0; i < 4; i++)                                                \
      bfr[i] = *(const bf16x8*)(lds_b + (wc*64 + i*16 + c15)*32 + hi*8);       \
    _Pragma("unroll")                                                          \
    for (int mi = 0; mi < 4; mi++)                                             \
      _Pragma("unroll")                                                        \
      for (int ni = 0; ni < 4; ni++)                                           \
        acc[mi][ni] = mfma16(af[mi], bfr[ni], acc[mi][ni]);                    \
  }

// Fused QKV projection: z=0 -> Q (scaled by QSCALE, [B,H,S,hd]),
// z=1 -> K ([B,H,S,hd]), z=2 -> V transposed ([B,H,hd,S]).
__global__ __launch_bounds__(256) void gemm_qkv(
    const bf16* __restrict__ A, const bf16* __restrict__ Wb3,
    const float* __restrict__ bq, const float* __restrict__ bk,
    const float* __restrict__ bv,
    bf16* __restrict__ Qb, bf16* __restrict__ Kb, bf16* __restrict__ Vtb)
{
  int z = blockIdx.z;
  const bf16* W = Wb3 + (size_t)z * WELEMS;
  const float* bias = (z == 0) ? bq : (z == 1) ? bk : bv;
  GEMM_CORE(A, W)

  float sc = (z == 0) ? QSCALE : 1.0f;
#pragma unroll
  for (int mi = 0; mi < 4; mi++) {
#pragma unroll
    for (int ni = 0; ni < 4; ni++) {
      int col = n0 + wc*64 + ni*16 + c15;
      float bvv = bias[col];
      int row = m0 + wr*64 + mi*16 + hi*4;
      int b = row >> 11, s = row & 2047;
      int h = col >> 6,  d = col & 63;
      if (z < 2) {
        bf16* C = z ? Kb : Qb;
#pragma unroll
        for (int r = 0; r < 4; r++)
          C[((b*NH + h)*SEQ + (s + r))*HD + d] = (bf16)((acc[mi][ni][r] + bvv) * sc);
      } else {
        bf16x4 o;
#pragma unroll
        for (int r = 0; r < 4; r++) o[r] = (bf16)(acc[mi][ni][r] + bvv);
        *(bf16x4*)(Vtb + ((size_t)(b*NH + h)*HD + d)*SEQ + s) = o;
      }
    }
  }
}

// Output GEMM: float C = ctx @ Wo^T + bo
__global__ __launch_bounds__(256) void gemm_out(
    const bf16* __restrict__ A, const bf16* __restrict__ W,
    const float* __restrict__ bias, float* __restrict__ C)
{
  GEMM_CORE(A, W)
#pragma unroll
  for (int mi = 0; mi < 4; mi++) {
#pragma unroll
    for (int ni = 0; ni < 4; ni++) {
      int col = n0 + wc*64 + ni*16 + c15;
      float bvv = bias[col];
      int row = m0 + wr*64 + mi*16 + hi*4;
#pragma unroll
      for (int r = 0; r < 4; r++)
        C[(row + r)*DM + col] = acc[mi][ni][r] + bvv;
    }
  }
}

// ---- attn v9 phase helpers -------------------------------------------------
// QK(it): st[qt][kvt] = K-tile · Q^T  (zero-init via shared zz, C!=D on MFMA)
__device__ __forceinline__ void qk_phase(
    f32x16 (&st)[2][2], const bf16* __restrict__ ktb,
    const bf16x8 (&qf)[2][4], int l31, int hi, int l7)
{
  f32x16 zz = {};
  __builtin_amdgcn_s_setprio(1);
#pragma unroll
  for (int kvt = 0; kvt < 2; kvt++) {
    int rowb = (kvt*32 + l31) * 64;      // row&7 == l7
    {
      bf16x8 kf = *(const bf16x8*)(ktb + rowb + (((0*2 + hi) ^ l7) * 8));
      st[0][kvt] = mfma32(kf, qf[0][0], zz);
      st[1][kvt] = mfma32(kf, qf[1][0], zz);
    }
#pragma unroll
    for (int dblk = 1; dblk < 4; dblk++) {
      bf16x8 kf = *(const bf16x8*)(ktb + rowb + (((dblk*2 + hi) ^ l7) * 8));
      st[0][kvt] = mfma32(kf, qf[0][dblk], st[0][kvt]);
      st[1][kvt] = mfma32(kf, qf[1][dblk], st[1][kvt]);
    }
  }
  __builtin_amdgcn_s_setprio(0);
}

// softmax+PV(it): exp2 raw (no-max, data-bounded), pack via cvtpk+permlane,
// row-sum from the bf16-ROUNDED pa words (consistent with PV numerator),
// then PV MFMA. Independent of the QK(it+1) MFMA stream -> co-schedules.
__device__ __forceinline__ void sm_pv_phase(
    f32x16 (&st)[2][2], const bf16* __restrict__ vtb,
    f32x16 (&po)[2][2], float (&lrun)[2], int l31, int hi, int l7)
{
  bf16x8 pa[2][2][2];                    // [qt][kvt][cp]
#pragma unroll
  for (int qt = 0; qt < 2; qt++) {
#pragma unroll
    for (int kvt = 0; kvt < 2; kvt++)
#pragma unroll
      for (int i = 0; i < 16; i++)
        st[qt][kvt][i] = exp2a(st[qt][kvt][i]);
#pragma unroll
    for (int kvt = 0; kvt < 2; kvt++)
#pragma unroll
      for (int cp = 0; cp < 2; cp++) {
        int m0 = 2*cp, m1 = 2*cp + 1;
        unsigned w0a = cvtpk(st[qt][kvt][4*m0+0], st[qt][kvt][4*m0+1]);
        unsigned w1a = cvtpk(st[qt][kvt][4*m0+2], st[qt][kvt][4*m0+3]);
        unsigned w0b = cvtpk(st[qt][kvt][4*m1+0], st[qt][kvt][4*m1+1]);
        unsigned w1b = cvtpk(st[qt][kvt][4*m1+2], st[qt][kvt][4*m1+3]);
        asm("v_permlane32_swap_b32 %0, %1" : "+v"(w0a), "+v"(w0b));
        asm("v_permlane32_swap_b32 %0, %1" : "+v"(w1a), "+v"(w1b));
        pa[qt][kvt][cp] = __builtin_bit_cast(bf16x8, (u32x4v){w0a, w1a, w0b, w1b});
      }
    // lane owns row q=l31's 32 kv values across its pa words (A-frag layout)
    float rs = 0.f;
#pragma unroll
    for (int kvt = 0; kvt < 2; kvt++)
#pragma unroll
      for (int cp = 0; cp < 2; cp++) {
        u32x4v w = __builtin_bit_cast(u32x4v, pa[qt][kvt][cp]);
#pragma unroll
        for (int j = 0; j < 4; j++) {
          rs += __builtin_bit_cast(float, w[j] << 16);
          rs += __builtin_bit_cast(float, w[j] & 0xffff0000u);
        }
      }
    lrun[qt] += rs;
  }
  __builtin_amdgcn_s_setprio(1);
#pragma unroll
  for (int dt = 0; dt < 2; dt++) {
    int rowb = (dt*32 + l31) * 64;       // row&7 == l7
#pragma unroll
    for (int c = 0; c < 4; c++) {
      bf16x8 vf = *(const bf16x8*)(vtb + rowb + (((c*2 + hi) ^ l7) * 8));
      po[0][dt] = mfma32(pa[0][c >> 1][c & 1], vf, po[0][dt]);
      po[1][dt] = mfma32(pa[1][c >> 1][c & 1], vf, po[1][dt]);
    }
  }
  __builtin_amdgcn_s_setprio(0);
}

// Flash attention v9: T15 att[2] double-pipeline. Per sub-iter:
//   vmcnt(4) -> s_barrier -> STAGE(it+2) -> QK(it) [MFMA] || SM+PV(it-1) [VALU+MFMA]
// stA/stB alternate (x2 unroll, static idx). 4 LDS buffers (64KB): PV(it-1)
// reads (it-1)%4 while STAGE writes (it+2)%4 — distinct; WAR by iter-it barrier.
__global__ __launch_bounds__(256, 2) void attn(
    const bf16* __restrict__ Q, const bf16* __restrict__ Kin,
    const bf16* __restrict__ Vt, bf16* __restrict__ ctx)
{
  __shared__ __align__(16) bf16 kt[4][64*64];   // [kv][d], 16B-unit swz: c8 ^= (kv&7)
  __shared__ __align__(16) bf16 vt[4][64*64];   // [d][kv], same swizzle

  int tid = threadIdx.x, wid = tid >> 6, lane = tid & 63;
  int l31 = lane & 31, hi = lane >> 5, l7 = lane & 7;

  // XCD-chunked bijective swizzle over 512 blocks: each XCD gets 8 bh (4MB K/V)
  int orig = blockIdx.y * gridDim.x + blockIdx.x;
  int swz  = (orig & 7) * 64 + (orig >> 3);
  int bh   = swz >> 3, q0 = (swz & 7) * 256;

  const bf16* Qp = Q   + (size_t)bh*SEQ*HD;
  const bf16* Kp = Kin + (size_t)bh*SEQ*HD;
  const bf16* Vp = Vt  + (size_t)bh*HD*SEQ;
  int qw = q0 + wid*64;                    // wave's 64 q rows (2 tiles of 32)

  bf16x8 qf[2][4];
#pragma unroll
  for (int qt = 0; qt < 2; qt++)
#pragma unroll
    for (int dblk = 0; dblk < 4; dblk++)
      qf[qt][dblk] = *(const bf16x8*)(Qp + (size_t)(qw + qt*32 + l31)*HD + dblk*16 + hi*8);

  f32x16 po[2][2] = {};                    // [qt][dt]; row q=R(reg,hi), col d=dt*32+l31
  float lrun[2] = {0.f, 0.f};              // lane-local half row-sums (bf16-consistent)
  f32x16 stA[2][2], stB[2][2];             // double pipeline state

  int r8 = lane >> 3;
  int c16s = (lane & 7) ^ r8;              // pre-swizzled source 16B-unit

#define STAGE(buf, kv0)                                                        \
  {                                                                            \
    _Pragma("unroll")                                                          \
    for (int op = 0; op < 2; op++) {                                           \
      int rowl = wid*16 + op*8 + r8;                                           \
      gload16(&kt[buf][(wid*16 + op*8)*64], Kp + (size_t)((kv0) + rowl)*HD + c16s*8); \
      gload16(&vt[buf][(wid*16 + op*8)*64], Vp + (size_t)rowl*SEQ + (kv0) + c16s*8);  \
    }                                                                          \
  }

#define TOP(itv)                                                               \
  {                                                                            \
    if ((itv) < NT - 1) { asm volatile("s_waitcnt vmcnt(4)" ::: "memory"); }   \
    else                { asm volatile("s_waitcnt vmcnt(0)" ::: "memory"); }   \
    __builtin_amdgcn_s_barrier();                                              \
    asm volatile("" ::: "memory");                                             \
    if ((itv) + 2 < NT) STAGE(((itv) + 2) & 3, ((itv) + 2) * 64);              \
  }

  const int NT = SEQ / 64;                 // 32 (even)
  STAGE(0, 0);
  STAGE(1, 64);

  for (int itb = 0; itb < NT; itb += 2) {
    // ---- sub-iter even: it = itb ----
    TOP(itb)
    qk_phase(stA, &kt[itb & 3][0], qf, l31, hi, l7);
    if (itb > 0)
      sm_pv_phase(stB, &vt[(itb - 1) & 3][0], po, lrun, l31, hi, l7);

    // ---- sub-iter odd: it = itb + 1 ----
    TOP(itb + 1)
    qk_phase(stB, &kt[(itb + 1) & 3][0], qf, l31, hi, l7);
    sm_pv_phase(stA, &vt[itb & 3][0], po, lrun, l31, hi, l7);
  }
  // epilogue: finish last tile
  sm_pv_phase(stB, &vt[(NT - 1) & 3][0], po, lrun, l31, hi, l7);
#undef STAGE
#undef TOP

  // ---- epilogue: combine half-sums, normalize, write ctx
  int b = bh >> 4, h = bh & 15;
#pragma unroll
  for (int qt = 0; qt < 2; qt++) {
    float lf  = lrun[qt] + __shfl_xor(lrun[qt], 32, 64);  // full row sum, q=l31
    float inv = 1.0f / lf;
#pragma unroll
    for (int reg = 0; reg < 16; reg++) {
      int qq = (reg & 3) + 8*(reg >> 2) + 4*hi;
      float iq = __shfl(inv, qq, 64);      // inv of output-row q (lane qq owns it)
      int s = qw + qt*32 + qq;
      bf16* dst = ctx + (size_t)(b*SEQ + s)*DM + h*HD + l31;
      dst[0]  = (bf16)(po[qt][0][reg] * iq);
      dst[32] = (bf16)(po[qt][1][reg] * iq);
    }
  }
}

extern "C" void kernel_launch(void* const* d_in, const int* in_sizes, int n_in,
                              void* d_out, int out_size, void* d_ws, size_t ws_size,
                              hipStream_t stream)
{
  const float* x  = (const float*)d_in[0];
  const float* Wq = (const float*)d_in[1];
  const float* bq = (const float*)d_in[2];
  const float* Wk = (const float*)d_in[3];
  const float* bk = (const float*)d_in[4];
  const float* Wv = (const float*)d_in[5];
  const float* bv = (const float*)d_in[6];
  const float* Wo = (const float*)d_in[7];
  const float* bo = (const float*)d_in[8];

  bf16* ws  = (bf16*)d_ws;
  bf16* xb  = ws;                          // [8192][1024] bf16 x
  bf16* Wb  = ws + ELEMS;                  // 4 x [1024][1024] bf16 weights
  bf16* Qb  = ws + ELEMS + 4*WELEMS;       // [B,H,S,hd] (pre-scaled)
  bf16* Kb  = Qb + ELEMS;
  bf16* Vtb = Kb + ELEMS;                  // [B,H,hd,S]
  bf16* ctx = xb;                          // reuse x slot (dead after projections)

  dim3 blk(256);

  cvt_all<<<dim3(ELEMS/1024, 5), blk, 0, stream>>>(x, xb, Wq, Wk, Wv, Wo, Wb);
  gemm_qkv<<<dim3(DM/128, MTOT/128, 3), blk, 0, stream>>>(
      xb, Wb, bq, bk, bv, Qb, Kb, Vtb);
  attn<<<dim3(SEQ/256, BHN), blk, 0, stream>>>(Qb, Kb, Vtb, ctx);
  gemm_out<<<dim3(DM/128, MTOT/128), blk, 0, stream>>>(
      ctx, Wb + 3*WELEMS, bo, (float*)d_out);
}

// Round 11
// 196.447 us; speedup vs baseline: 1.0358x; 1.0358x over previous
//
#include <hip/hip_runtime.h>

typedef __bf16 bf16;
typedef __bf16 bf16x4 __attribute__((ext_vector_type(4)));
typedef __bf16 bf16x8 __attribute__((ext_vector_type(8)));
typedef float  f32x4  __attribute__((ext_vector_type(4)));
typedef float  f32x16 __attribute__((ext_vector_type(16)));
typedef unsigned int u32x4v __attribute__((ext_vector_type(4)));

#define NB   4
#define SEQ  2048
#define DM   1024
#define NH   16
#define HD   64
#define BHN  (NB*NH)       // 64
#define MTOT (NB*SEQ)      // 8192
#define ELEMS ((size_t)MTOT*DM)  // 8388608
#define WELEMS (DM*DM)     // 1048576
#define QSCALE 0.18033688011112042f   // 0.125 * log2(e): scores in log2 units

__device__ __forceinline__ void gload16(void* lds, const void* g) {
  __builtin_amdgcn_global_load_lds(
      (const __attribute__((address_space(1))) void*)g,
      (__attribute__((address_space(3))) void*)lds, 16, 0, 0);
}

__device__ __forceinline__ f32x4 mfma16(bf16x8 a, bf16x8 b, f32x4 c) {
  return __builtin_amdgcn_mfma_f32_16x16x32_bf16(a, b, c, 0, 0, 0);
}
__device__ __forceinline__ f32x16 mfma32(bf16x8 a, bf16x8 b, f32x16 c) {
  return __builtin_amdgcn_mfma_f32_32x32x16_bf16(a, b, c, 0, 0, 0);
}
__device__ __forceinline__ unsigned cvtpk(float lo, float hi) {
  unsigned r;
  asm("v_cvt_pk_bf16_f32 %0, %1, %2" : "=v"(r) : "v"(lo), "v"(hi));
  return r;
}
__device__ __forceinline__ float exp2a(float x) {   // D = 2^x
  float r;
  asm("v_exp_f32 %0, %1" : "=v"(r) : "v"(x));
  return r;
}

// fp32 -> bf16 conversion: y=0..3 -> W_y, y=4 -> x
__global__ __launch_bounds__(256) void cvt_all(
    const float* __restrict__ x, bf16* __restrict__ xb,
    const float* __restrict__ w0, const float* __restrict__ w1,
    const float* __restrict__ w2, const float* __restrict__ w3,
    bf16* __restrict__ wb)
{
  int y = blockIdx.y;
  const float* src; bf16* dst; int nblk;
  if (y < 4) {
    src = (y == 0) ? w0 : (y == 1) ? w1 : (y == 2) ? w2 : w3;
    dst = wb + (size_t)y * WELEMS;
    nblk = WELEMS / 1024;
  } else {
    src = x; dst = xb; nblk = (int)(ELEMS / 1024);
  }
  if (blockIdx.x >= nblk) return;
  int i = blockIdx.x * 1024 + threadIdx.x * 4;
  f32x4 v = *(const f32x4*)(src + i);
  bf16x4 o;
#pragma unroll
  for (int j = 0; j < 4; j++) o[j] = (bf16)v[j];
  *(bf16x4*)(dst + i) = o;
}

// ---- m97-structure GEMM core (kept for gemm_out)
#define GEMM_CORE(A_, W_)                                                      \
  __shared__ __align__(16) bf16 lds_a[128*32];                                 \
  __shared__ __align__(16) bf16 lds_b[128*32];                                 \
  const int K = 1024;                                                          \
  int tid = threadIdx.x, wid = tid >> 6, lane = tid & 63;                      \
  int m0 = blockIdx.y * 128, n0 = blockIdx.x * 128;                            \
  int wr = wid >> 1, wc = wid & 1;                                             \
  int c15 = lane & 15, hi = lane >> 4;                                         \
  int srow = lane >> 2, scol = (lane & 3) * 8;                                 \
  const bf16* gA = (A_) + (m0 + wid*32 + srow) * K + scol;                     \
  const bf16* gB = (W_) + (n0 + wid*32 + srow) * K + scol;                     \
  bf16* la = lds_a + wid*1024;                                                 \
  bf16* lb = lds_b + wid*1024;                                                 \
  f32x4 acc[4][4] = {};                                                        \
  for (int k0 = 0; k0 < K; k0 += 32) {                                         \
    __syncthreads();                                                           \
    gload16(la,       gA + k0);                                                \
    gload16(la + 512, gA + 16*K + k0);                                         \
    gload16(lb,       gB + k0);                                                \
    gload16(lb + 512, gB + 16*K + k0);                                         \
    __syncthreads();                                                           \
    bf16x8 af[4], bfr[4];                                                      \
    _Pragma("unroll")                                                          \
    for (int i = 0; i < 4; i++)                                                \
      af[i]  = *(const bf16x8*)(lds_a + (wr*64 + i*16 + c15)*32 + hi*8);       \
    _Pragma("unroll")                                                          \
    for (int i = 0; i < 4; i++)                                                \
      bfr[i] = *(const bf16x8*)(lds_b + (wc*64 + i*16 + c15)*32 + hi*8);       \
    _Pragma("unroll")                                                          \
    for (int mi = 0; mi < 4; mi++)                                             \
      _Pragma("unroll")                                                        \
      for (int ni = 0; ni < 4; ni++)                                           \
        acc[mi][ni] = mfma16(af[mi], bfr[ni], acc[mi][ni]);                    \
  }

// Output GEMM: float C = ctx @ Wo^T + bo  (m97 structure, at its ceiling)
__global__ __launch_bounds__(256) void gemm_out(
    const bf16* __restrict__ A, const bf16* __restrict__ W,
    const float* __restrict__ bias, float* __restrict__ C)
{
  GEMM_CORE(A, W)
#pragma unroll
  for (int mi = 0; mi < 4; mi++) {
#pragma unroll
    for (int ni = 0; ni < 4; ni++) {
      int col = n0 + wc*64 + ni*16 + c15;
      float bvv = bias[col];
      int row = m0 + wr*64 + mi*16 + hi*4;
#pragma unroll
      for (int r = 0; r < 4; r++)
        C[(row + r)*DM + col] = acc[mi][ni][r] + bvv;
    }
  }
}

// Fused QKV GEMM, 4-phase counted-vmcnt template (T2+T3/T4+T5 port):
// C[8192,3072] = x @ [Wq|Wk|Wv]^T + bias, scattered to Q/K [B,H,S,hd] and
// Vt [B,H,hd,S]. BM=256 BN=128 BK=64, 8 waves (4M x 2N), per-wave 64x64.
// Staging units per K-tile: {B, A-half0, A-half1}, 2 gload16/wave each,
// issued JIT at P0/P1/P2 so A-half1 stays in flight until P2 (vmcnt(4)).
// LDS 96KB (1 block/CU), XOR-swizzled tiles (attn-proven pattern).
__global__ __launch_bounds__(512, 2) void gemm_qkv256(
    const bf16* __restrict__ A, const bf16* __restrict__ Wb3,
    const float* __restrict__ bq, const float* __restrict__ bk,
    const float* __restrict__ bv,
    bf16* __restrict__ Qb, bf16* __restrict__ Kb, bf16* __restrict__ Vtb)
{
  __shared__ __align__(16) bf16 la[2][256*64];   // A tile [row][k], swz u^=(row&7)
  __shared__ __align__(16) bf16 lb[2][128*64];   // W tile [row][k], same swz

  const int K = 1024;
  int tid = threadIdx.x, wid = tid >> 6, lane = tid & 63;
  int wr = wid >> 1, wc = wid & 1;               // 4M x 2N wave grid
  int c15 = lane & 15, hi = lane >> 4, l7 = lane & 7;

  // XCD-chunked bijective swizzle over 768 blocks (96/XCD; W-panels L2-resident)
  int orig = blockIdx.x;
  int swz  = (orig & 7) * 96 + (orig >> 3);
  int by = swz & 31, bx = swz >> 5;
  int m0 = by * 256, n0 = bx * 128;
  int z  = n0 >> 10;                             // 0=Q 1=K 2=V (block-uniform)
  const float* bias = (z == 0) ? bq : (z == 1) ? bk : bv;

  int r8 = lane >> 3;
  int cu = (lane & 7) ^ r8;                      // pre-swizzled source 16B unit

  const bf16* gA = A   + (size_t)m0 * K;
  const bf16* gW = Wb3 + (size_t)n0 * K;

  // stage A-half h (128 rows) / B (128 rows) of K-tile kt into buffer buf
#define STA(buf, h, kt)                                                        \
  {                                                                            \
    _Pragma("unroll")                                                          \
    for (int op = 0; op < 2; op++) {                                           \
      int rowl = (h)*128 + wid*16 + op*8 + r8;                                 \
      gload16(&la[buf][((h)*128 + wid*16 + op*8)*64],                          \
              gA + (size_t)rowl*K + (kt)*64 + cu*8);                           \
    }                                                                          \
  }
#define STB(buf, kt)                                                           \
  {                                                                            \
    _Pragma("unroll")                                                          \
    for (int op = 0; op < 2; op++) {                                           \
      int rowl = wid*16 + op*8 + r8;                                           \
      gload16(&lb[buf][(wid*16 + op*8)*64],                                    \
              gW + (size_t)rowl*K + (kt)*64 + cu*8);                           \
    }                                                                          \
  }

  f32x4 acc[4][4] = {};                          // [mi][ni]; mi<2 half0, mi>=2 half1
  const int NT = K / 64;                         // 16 K-tiles

  // prologue: queue order [B(0), Ah0(0), Ah1(0)] = 6 ops
  STB(0, 0);
  STA(0, 0, 0);
  STA(0, 1, 0);

  for (int t = 0; t < NT; ++t) {
    int cb = t & 1, nb = cb ^ 1;
    // TOP: own B(t),Ah0(t) landed (Ah1(t) = 2 newest may fly); cross-wave via barrier
    asm volatile("s_waitcnt vmcnt(2)" ::: "memory");
    __builtin_amdgcn_s_barrier();
    asm volatile("" ::: "memory");

    bf16x8 af0[2][2], af1[2][2], bf0[2][2], bf1[2][2];

    // ---- P0: read A(half0 strips) + B(nh0); stage B(t+1); MFMA q(0,0)
#pragma unroll
    for (int mi = 0; mi < 2; mi++)
#pragma unroll
      for (int kk = 0; kk < 2; kk++)
        af0[mi][kk] = *(const bf16x8*)(&la[cb][(wr*32 + mi*16 + c15)*64 + (((kk*4 + hi) ^ l7) * 8)]);
#pragma unroll
    for (int ni = 0; ni < 2; ni++)
#pragma unroll
      for (int kk = 0; kk < 2; kk++)
        bf0[ni][kk] = *(const bf16x8*)(&lb[cb][(wc*64 + ni*16 + c15)*64 + (((kk*4 + hi) ^ l7) * 8)]);
    if (t + 1 < NT) STB(nb, t + 1);
    __builtin_amdgcn_s_setprio(1);
#pragma unroll
    for (int mi = 0; mi < 2; mi++)
#pragma unroll
      for (int ni = 0; ni < 2; ni++)
#pragma unroll
        for (int kk = 0; kk < 2; kk++)
          acc[mi][ni] = mfma16(af0[mi][kk], bf0[ni][kk], acc[mi][ni]);
    __builtin_amdgcn_s_setprio(0);

    // ---- P1: read B(nh1); stage A-half0(t+1); MFMA q(0,1)
#pragma unroll
    for (int ni = 0; ni < 2; ni++)
#pragma unroll
      for (int kk = 0; kk < 2; kk++)
        bf1[ni][kk] = *(const bf16x8*)(&lb[cb][(wc*64 + 32 + ni*16 + c15)*64 + (((kk*4 + hi) ^ l7) * 8)]);
    if (t + 1 < NT) STA(nb, 0, t + 1);
    __builtin_amdgcn_s_setprio(1);
#pragma unroll
    for (int mi = 0; mi < 2; mi++)
#pragma unroll
      for (int ni = 0; ni < 2; ni++)
#pragma unroll
        for (int kk = 0; kk < 2; kk++)
          acc[mi][2 + ni] = mfma16(af0[mi][kk], bf1[ni][kk], acc[mi][2 + ni]);
    __builtin_amdgcn_s_setprio(0);

    // MID: own Ah1(t) landed (B(t+1),Ah0(t+1) = 4 newest may fly); cross-wave barrier
    if (t + 1 < NT) { asm volatile("s_waitcnt vmcnt(4)" ::: "memory"); }
    else            { asm volatile("s_waitcnt vmcnt(0)" ::: "memory"); }
    __builtin_amdgcn_s_barrier();
    asm volatile("" ::: "memory");

    // ---- P2: read A(half1 strips); stage A-half1(t+1); MFMA q(1,1)
#pragma unroll
    for (int mi = 0; mi < 2; mi++)
#pragma unroll
      for (int kk = 0; kk < 2; kk++)
        af1[mi][kk] = *(const bf16x8*)(&la[cb][(128 + wr*32 + mi*16 + c15)*64 + (((kk*4 + hi) ^ l7) * 8)]);
    if (t + 1 < NT) STA(nb, 1, t + 1);
    __builtin_amdgcn_s_setprio(1);
#pragma unroll
    for (int mi = 0; mi < 2; mi++)
#pragma unroll
      for (int ni = 0; ni < 2; ni++)
#pragma unroll
        for (int kk = 0; kk < 2; kk++)
          acc[2 + mi][2 + ni] = mfma16(af1[mi][kk], bf1[ni][kk], acc[2 + mi][2 + ni]);
    __builtin_amdgcn_s_setprio(0);

    // ---- P3: MFMA q(1,0)  (bf0 kept live)
    __builtin_amdgcn_s_setprio(1);
#pragma unroll
    for (int mi = 0; mi < 2; mi++)
#pragma unroll
      for (int ni = 0; ni < 2; ni++)
#pragma unroll
        for (int kk = 0; kk < 2; kk++)
          acc[2 + mi][ni] = mfma16(af1[mi][kk], bf0[ni][kk], acc[2 + mi][ni]);
    __builtin_amdgcn_s_setprio(0);
  }
#undef STA
#undef STB

  // ---- epilogue: bias + scatter (Q scaled; V transposed)
#pragma unroll
  for (int mi = 0; mi < 4; mi++) {
    int rbase = m0 + ((mi < 2) ? (wr*32 + mi*16) : (128 + wr*32 + (mi - 2)*16)) + hi*4;
#pragma unroll
    for (int ni = 0; ni < 4; ni++) {
      int n  = n0 + wc*64 + ni*16 + c15;
      int cz = n & 1023;
      float bvv = bias[cz];
      int h = cz >> 6, d = cz & 63;
      int b = rbase >> 11, s = rbase & 2047;
      if (z < 2) {
        bf16* C = z ? Kb : Qb;
        float sc = z ? 1.0f : QSCALE;
#pragma unroll
        for (int r = 0; r < 4; r++)
          C[((b*NH + h)*SEQ + (s + r))*HD + d] = (bf16)((acc[mi][ni][r] + bvv) * sc);
      } else {
        bf16x4 o;
#pragma unroll
        for (int r = 0; r < 4; r++) o[r] = (bf16)(acc[mi][ni][r] + bvv);
        *(bf16x4*)(Vtb + ((size_t)(b*NH + h)*HD + d)*SEQ + s) = o;
      }
    }
  }
}

// Flash attention v5 (round-7 best, verbatim): 2 q-tiles/wave, no-max exp2
// softmax, MFMA row-sums, KVBLK=128 per barrier window, swizzled dbuf LDS.
__global__ __launch_bounds__(256, 2) void attn(
    const bf16* __restrict__ Q, const bf16* __restrict__ Kin,
    const bf16* __restrict__ Vt, bf16* __restrict__ ctx)
{
  __shared__ __align__(16) bf16 kt[2][128*64];  // [kv][d], 16B-unit swz: c8 ^= (kv&7)
  __shared__ __align__(16) bf16 vt[2][64*128];  // [d][kv], 16B-unit swz: c16 ^= (d&7)

  int tid = threadIdx.x, wid = tid >> 6, lane = tid & 63;
  int l31 = lane & 31, hi = lane >> 5, l7 = lane & 7;

  int orig = blockIdx.y * gridDim.x + blockIdx.x;
  int swz  = (orig & 7) * 64 + (orig >> 3);
  int bh   = swz >> 3, q0 = (swz & 7) * 256;

  const bf16* Qp = Q   + (size_t)bh*SEQ*HD;
  const bf16* Kp = Kin + (size_t)bh*SEQ*HD;
  const bf16* Vp = Vt  + (size_t)bh*HD*SEQ;
  int qw = q0 + wid*64;

  bf16x8 qf[2][4];
#pragma unroll
  for (int qt = 0; qt < 2; qt++)
#pragma unroll
    for (int dblk = 0; dblk < 4; dblk++)
      qf[qt][dblk] = *(const bf16x8*)(Qp + (size_t)(qw + qt*32 + l31)*HD + dblk*16 + hi*8);

  f32x16 po[2][2]  = {};
  f32x16 posum[2]  = {};

  bf16x8 onesv;
#pragma unroll
  for (int j = 0; j < 8; j++) onesv[j] = (bf16)1.0f;

  int r8 = lane >> 3;
  int ck = (lane & 7) ^ r8;
  int r16 = lane >> 4, c16v = lane & 15;

#define STAGE(buf, kv0)                                                        \
  {                                                                            \
    _Pragma("unroll")                                                          \
    for (int op = 0; op < 4; op++) {                                           \
      int rk = wid*32 + op*8 + r8;                                             \
      gload16(&kt[buf][(wid*32 + op*8)*64],                                    \
              Kp + (size_t)((kv0) + rk)*HD + ck*8);                            \
      int rv = wid*16 + op*4 + r16;                                            \
      gload16(&vt[buf][(wid*16 + op*4)*128],                                   \
              Vp + (size_t)rv*SEQ + (kv0) + ((c16v ^ (rv & 7))*8));            \
    }                                                                          \
  }

  STAGE(0, 0);
  __syncthreads();

  for (int it = 0; it < SEQ/128; ++it) {
    int cur = it & 1;
    if (it < SEQ/128 - 1) STAGE(cur ^ 1, (it + 1) * 128);

#pragma unroll
    for (int sub = 0; sub < 2; sub++) {
      f32x16 st[2][2] = {};
      __builtin_amdgcn_s_setprio(1);
#pragma unroll
      for (int kvt = 0; kvt < 2; kvt++) {
        int rowb = (sub*64 + kvt*32 + l31) * 64;
#pragma unroll
        for (int dblk = 0; dblk < 4; dblk++) {
          bf16x8 kf = *(const bf16x8*)(&kt[cur][rowb + (((dblk*2 + hi) ^ l7) * 8)]);
          st[0][kvt] = mfma32(kf, qf[0][dblk], st[0][kvt]);
          st[1][kvt] = mfma32(kf, qf[1][dblk], st[1][kvt]);
        }
      }
      __builtin_amdgcn_s_setprio(0);

      bf16x8 pa[2][2][2];
#pragma unroll
      for (int qt = 0; qt < 2; qt++) {
#pragma unroll
        for (int kvt = 0; kvt < 2; kvt++)
#pragma unroll
          for (int i = 0; i < 16; i++)
            st[qt][kvt][i] = exp2a(st[qt][kvt][i]);
#pragma unroll
        for (int kvt = 0; kvt < 2; kvt++)
#pragma unroll
          for (int cp = 0; cp < 2; cp++) {
            int m0 = 2*cp, m1 = 2*cp + 1;
            unsigned w0a = cvtpk(st[qt][kvt][4*m0+0], st[qt][kvt][4*m0+1]);
            unsigned w1a = cvtpk(st[qt][kvt][4*m0+2], st[qt][kvt][4*m0+3]);
            unsigned w0b = cvtpk(st[qt][kvt][4*m1+0], st[qt][kvt][4*m1+1]);
            unsigned w1b = cvtpk(st[qt][kvt][4*m1+2], st[qt][kvt][4*m1+3]);
            asm("v_permlane32_swap_b32 %0, %1" : "+v"(w0a), "+v"(w0b));
            asm("v_permlane32_swap_b32 %0, %1" : "+v"(w1a), "+v"(w1b));
            pa[qt][kvt][cp] = __builtin_bit_cast(bf16x8, (u32x4v){w0a, w1a, w0b, w1b});
          }
      }

      __builtin_amdgcn_s_setprio(1);
#pragma unroll
      for (int dt = 0; dt < 2; dt++) {
        int rowb = (dt*32 + l31) * 128;
#pragma unroll
        for (int c = 0; c < 4; c++) {
          bf16x8 vf = *(const bf16x8*)(&vt[cur][rowb + ((sub*8 + ((c*2 + hi) ^ l7)) * 8)]);
          po[0][dt] = mfma32(pa[0][c >> 1][c & 1], vf, po[0][dt]);
          po[1][dt] = mfma32(pa[1][c >> 1][c & 1], vf, po[1][dt]);
        }
      }
#pragma unroll
      for (int c = 0; c < 4; c++) {
        posum[0] = mfma32(pa[0][c >> 1][c & 1], onesv, posum[0]);
        posum[1] = mfma32(pa[1][c >> 1][c & 1], onesv, posum[1]);
      }
      __builtin_amdgcn_s_setprio(0);
    }

    __syncthreads();
  }
#undef STAGE

  int b = bh >> 4, h = bh & 15;
#pragma unroll
  for (int qt = 0; qt < 2; qt++)
#pragma unroll
    for (int reg = 0; reg < 16; reg++) {
      int qq = (reg & 3) + 8*(reg >> 2) + 4*hi;
      float inv = 1.0f / posum[qt][reg];
      int s = qw + qt*32 + qq;
      bf16* dst = ctx + (size_t)(b*SEQ + s)*DM + h*HD + l31;
      dst[0]  = (bf16)(po[qt][0][reg] * inv);
      dst[32] = (bf16)(po[qt][1][reg] * inv);
    }
}

extern "C" void kernel_launch(void* const* d_in, const int* in_sizes, int n_in,
                              void* d_out, int out_size, void* d_ws, size_t ws_size,
                              hipStream_t stream)
{
  const float* x  = (const float*)d_in[0];
  const float* Wq = (const float*)d_in[1];
  const float* bq = (const float*)d_in[2];
  const float* Wk = (const float*)d_in[3];
  const float* bk = (const float*)d_in[4];
  const float* Wv = (const float*)d_in[5];
  const float* bv = (const float*)d_in[6];
  const float* Wo = (const float*)d_in[7];
  const float* bo = (const float*)d_in[8];

  bf16* ws  = (bf16*)d_ws;
  bf16* xb  = ws;                          // [8192][1024] bf16 x
  bf16* Wb  = ws + ELEMS;                  // 4 x [1024][1024] bf16 weights (q,k,v,o)
  bf16* Qb  = ws + ELEMS + 4*WELEMS;       // [B,H,S,hd] (pre-scaled)
  bf16* Kb  = Qb + ELEMS;
  bf16* Vtb = Kb + ELEMS;                  // [B,H,hd,S]
  bf16* ctx = xb;                          // reuse x slot (dead after projections)

  cvt_all<<<dim3(ELEMS/1024, 5), dim3(256), 0, stream>>>(x, xb, Wq, Wk, Wv, Wo, Wb);
  gemm_qkv256<<<dim3(768), dim3(512), 0, stream>>>(
      xb, Wb, bq, bk, bv, Qb, Kb, Vtb);
  attn<<<dim3(SEQ/256, BHN), dim3(256), 0, stream>>>(Qb, Kb, Vtb, ctx);
  gemm_out<<<dim3(DM/128, MTOT/128), dim3(256), 0, stream>>>(
      ctx, Wb + 3*WELEMS, bo, (float*)d_out);
}

// Round 12
// 183.983 us; speedup vs baseline: 1.1060x; 1.0677x over previous
//
#include <hip/hip_runtime.h>

typedef __bf16 bf16;
typedef __bf16 bf16x4 __attribute__((ext_vector_type(4)));
typedef __bf16 bf16x8 __attribute__((ext_vector_type(8)));
typedef float  f32x4  __attribute__((ext_vector_type(4)));
typedef float  f32x16 __attribute__((ext_vector_type(16)));
typedef unsigned int u32x4v __attribute__((ext_vector_type(4)));

#define NB   4
#define SEQ  2048
#define DM   1024
#define NH   16
#define HD   64
#define BHN  (NB*NH)       // 64
#define MTOT (NB*SEQ)      // 8192
#define ELEMS ((size_t)MTOT*DM)  // 8388608
#define WELEMS (DM*DM)     // 1048576
#define QSCALE 0.18033688011112042f   // 0.125 * log2(e): scores in log2 units

__device__ __forceinline__ void gload16(void* lds, const void* g) {
  __builtin_amdgcn_global_load_lds(
      (const __attribute__((address_space(1))) void*)g,
      (__attribute__((address_space(3))) void*)lds, 16, 0, 0);
}

__device__ __forceinline__ f32x4 mfma16(bf16x8 a, bf16x8 b, f32x4 c) {
  return __builtin_amdgcn_mfma_f32_16x16x32_bf16(a, b, c, 0, 0, 0);
}
__device__ __forceinline__ f32x16 mfma32(bf16x8 a, bf16x8 b, f32x16 c) {
  return __builtin_amdgcn_mfma_f32_32x32x16_bf16(a, b, c, 0, 0, 0);
}
__device__ __forceinline__ unsigned cvtpk(float lo, float hi) {
  unsigned r;
  asm("v_cvt_pk_bf16_f32 %0, %1, %2" : "=v"(r) : "v"(lo), "v"(hi));
  return r;
}
__device__ __forceinline__ float exp2a(float x) {   // D = 2^x
  float r;
  asm("v_exp_f32 %0, %1" : "=v"(r) : "v"(x));
  return r;
}

// fp32 -> bf16 conversion: y=0..3 -> W_y, y=4 -> x
__global__ __launch_bounds__(256) void cvt_all(
    const float* __restrict__ x, bf16* __restrict__ xb,
    const float* __restrict__ w0, const float* __restrict__ w1,
    const float* __restrict__ w2, const float* __restrict__ w3,
    bf16* __restrict__ wb)
{
  int y = blockIdx.y;
  const float* src; bf16* dst; int nblk;
  if (y < 4) {
    src = (y == 0) ? w0 : (y == 1) ? w1 : (y == 2) ? w2 : w3;
    dst = wb + (size_t)y * WELEMS;
    nblk = WELEMS / 1024;
  } else {
    src = x; dst = xb; nblk = (int)(ELEMS / 1024);
  }
  if (blockIdx.x >= nblk) return;
  int i = blockIdx.x * 1024 + threadIdx.x * 4;
  f32x4 v = *(const f32x4*)(src + i);
  bf16x4 o;
#pragma unroll
  for (int j = 0; j < 4; j++) o[j] = (bf16)v[j];
  *(bf16x4*)(dst + i) = o;
}

// ---- m97-structure GEMM core (kept for gemm_out)
#define GEMM_CORE(A_, W_)                                                      \
  __shared__ __align__(16) bf16 lds_a[128*32];                                 \
  __shared__ __align__(16) bf16 lds_b[128*32];                                 \
  const int K = 1024;                                                          \
  int tid = threadIdx.x, wid = tid >> 6, lane = tid & 63;                      \
  int m0 = blockIdx.y * 128, n0 = blockIdx.x * 128;                            \
  int wr = wid >> 1, wc = wid & 1;                                             \
  int c15 = lane & 15, hi = lane >> 4;                                         \
  int srow = lane >> 2, scol = (lane & 3) * 8;                                 \
  const bf16* gA = (A_) + (m0 + wid*32 + srow) * K + scol;                     \
  const bf16* gB = (W_) + (n0 + wid*32 + srow) * K + scol;                     \
  bf16* la = lds_a + wid*1024;                                                 \
  bf16* lb = lds_b + wid*1024;                                                 \
  f32x4 acc[4][4] = {};                                                        \
  for (int k0 = 0; k0 < K; k0 += 32) {                                         \
    __syncthreads();                                                           \
    gload16(la,       gA + k0);                                                \
    gload16(la + 512, gA + 16*K + k0);                                         \
    gload16(lb,       gB + k0);                                                \
    gload16(lb + 512, gB + 16*K + k0);                                         \
    __syncthreads();                                                           \
    bf16x8 af[4], bfr[4];                                                      \
    _Pragma("unroll")                                                          \
    for (int i = 0; i < 4; i++)                                                \
      af[i]  = *(const bf16x8*)(lds_a + (wr*64 + i*16 + c15)*32 + hi*8);       \
    _Pragma("unroll")                                                          \
    for (int i = 0; i < 4; i++)                                                \
      bfr[i] = *(const bf16x8*)(lds_b + (wc*64 + i*16 + c15)*32 + hi*8);       \
    _Pragma("unroll")                                                          \
    for (int mi = 0; mi < 4; mi++)                                             \
      _Pragma("unroll")                                                        \
      for (int ni = 0; ni < 4; ni++)                                           \
        acc[mi][ni] = mfma16(af[mi], bfr[ni], acc[mi][ni]);                    \
  }

// Output GEMM: float C = ctx @ Wo^T + bo  (m97 structure, at its ceiling)
__global__ __launch_bounds__(256) void gemm_out(
    const bf16* __restrict__ A, const bf16* __restrict__ W,
    const float* __restrict__ bias, float* __restrict__ C)
{
  GEMM_CORE(A, W)
#pragma unroll
  for (int mi = 0; mi < 4; mi++) {
#pragma unroll
    for (int ni = 0; ni < 4; ni++) {
      int col = n0 + wc*64 + ni*16 + c15;
      float bvv = bias[col];
      int row = m0 + wr*64 + mi*16 + hi*4;
#pragma unroll
      for (int r = 0; r < 4; r++)
        C[(row + r)*DM + col] = acc[mi][ni][r] + bvv;
    }
  }
}

// Fused QKV GEMM, 4-phase counted-vmcnt template.
// FIX vs round 11: block->XCD map. Old map gave each XCD by=0..31 (all of x,
// 16MB >> 4MB L2) -> FETCH 200MB, L3-bound. New map: XCD i owns by in
// {4i..4i+3} (2MB of A, L2-resident across all 24 bx since reused), by
// varies fastest so 4 concurrent blocks share one 256KB W panel.
__global__ __launch_bounds__(512, 2) void gemm_qkv256(
    const bf16* __restrict__ A, const bf16* __restrict__ Wb3,
    const float* __restrict__ bq, const float* __restrict__ bk,
    const float* __restrict__ bv,
    bf16* __restrict__ Qb, bf16* __restrict__ Kb, bf16* __restrict__ Vtb)
{
  __shared__ __align__(16) bf16 la[2][256*64];   // A tile [row][k], swz u^=(row&7)
  __shared__ __align__(16) bf16 lb[2][128*64];   // W tile [row][k], same swz

  const int K = 1024;
  int tid = threadIdx.x, wid = tid >> 6, lane = tid & 63;
  int wr = wid >> 1, wc = wid & 1;               // 4M x 2N wave grid
  int c15 = lane & 15, hi = lane >> 4, l7 = lane & 7;

  // XCD-locality swizzle over 768 blocks = 32 by x 24 bx.
  int orig = blockIdx.x;
  int xcd = orig & 7, j = orig >> 3;             // j in 0..95
  int by = xcd * 4 + (j & 3);                    // XCD-owned contiguous M chunk
  int bx = j >> 2;                               // W panel varies slowest
  int m0 = by * 256, n0 = bx * 128;
  int z  = n0 >> 10;                             // 0=Q 1=K 2=V (block-uniform)
  const float* bias = (z == 0) ? bq : (z == 1) ? bk : bv;

  int r8 = lane >> 3;
  int cu = (lane & 7) ^ r8;                      // pre-swizzled source 16B unit

  const bf16* gA = A   + (size_t)m0 * K;
  const bf16* gW = Wb3 + (size_t)n0 * K;

#define STA(buf, h, kt)                                                        \
  {                                                                            \
    _Pragma("unroll")                                                          \
    for (int op = 0; op < 2; op++) {                                           \
      int rowl = (h)*128 + wid*16 + op*8 + r8;                                 \
      gload16(&la[buf][((h)*128 + wid*16 + op*8)*64],                          \
              gA + (size_t)rowl*K + (kt)*64 + cu*8);                           \
    }                                                                          \
  }
#define STB(buf, kt)                                                           \
  {                                                                            \
    _Pragma("unroll")                                                          \
    for (int op = 0; op < 2; op++) {                                           \
      int rowl = wid*16 + op*8 + r8;                                           \
      gload16(&lb[buf][(wid*16 + op*8)*64],                                    \
              gW + (size_t)rowl*K + (kt)*64 + cu*8);                           \
    }                                                                          \
  }

  f32x4 acc[4][4] = {};                          // [mi][ni]; mi<2 half0, mi>=2 half1
  const int NT = K / 64;                         // 16 K-tiles

  // prologue: queue order [B(0), Ah0(0), Ah1(0)] = 6 ops
  STB(0, 0);
  STA(0, 0, 0);
  STA(0, 1, 0);

  for (int t = 0; t < NT; ++t) {
    int cb = t & 1, nb = cb ^ 1;
    // TOP: own B(t),Ah0(t) landed (Ah1(t) = 2 newest may fly)
    asm volatile("s_waitcnt vmcnt(2)" ::: "memory");
    __builtin_amdgcn_s_barrier();
    asm volatile("" ::: "memory");

    bf16x8 af0[2][2], af1[2][2], bf0[2][2], bf1[2][2];

    // ---- P0: read A(half0 strips) + B(nh0); stage B(t+1); MFMA q(0,0)
#pragma unroll
    for (int mi = 0; mi < 2; mi++)
#pragma unroll
      for (int kk = 0; kk < 2; kk++)
        af0[mi][kk] = *(const bf16x8*)(&la[cb][(wr*32 + mi*16 + c15)*64 + (((kk*4 + hi) ^ l7) * 8)]);
#pragma unroll
    for (int ni = 0; ni < 2; ni++)
#pragma unroll
      for (int kk = 0; kk < 2; kk++)
        bf0[ni][kk] = *(const bf16x8*)(&lb[cb][(wc*64 + ni*16 + c15)*64 + (((kk*4 + hi) ^ l7) * 8)]);
    if (t + 1 < NT) STB(nb, t + 1);
    __builtin_amdgcn_s_setprio(1);
#pragma unroll
    for (int mi = 0; mi < 2; mi++)
#pragma unroll
      for (int ni = 0; ni < 2; ni++)
#pragma unroll
        for (int kk = 0; kk < 2; kk++)
          acc[mi][ni] = mfma16(af0[mi][kk], bf0[ni][kk], acc[mi][ni]);
    __builtin_amdgcn_s_setprio(0);

    // ---- P1: read B(nh1); stage A-half0(t+1); MFMA q(0,1)
#pragma unroll
    for (int ni = 0; ni < 2; ni++)
#pragma unroll
      for (int kk = 0; kk < 2; kk++)
        bf1[ni][kk] = *(const bf16x8*)(&lb[cb][(wc*64 + 32 + ni*16 + c15)*64 + (((kk*4 + hi) ^ l7) * 8)]);
    if (t + 1 < NT) STA(nb, 0, t + 1);
    __builtin_amdgcn_s_setprio(1);
#pragma unroll
    for (int mi = 0; mi < 2; mi++)
#pragma unroll
      for (int ni = 0; ni < 2; ni++)
#pragma unroll
        for (int kk = 0; kk < 2; kk++)
          acc[mi][2 + ni] = mfma16(af0[mi][kk], bf1[ni][kk], acc[mi][2 + ni]);
    __builtin_amdgcn_s_setprio(0);

    // MID: own Ah1(t) landed (B(t+1),Ah0(t+1) = 4 newest may fly)
    if (t + 1 < NT) { asm volatile("s_waitcnt vmcnt(4)" ::: "memory"); }
    else            { asm volatile("s_waitcnt vmcnt(0)" ::: "memory"); }
    __builtin_amdgcn_s_barrier();
    asm volatile("" ::: "memory");

    // ---- P2: read A(half1 strips); stage A-half1(t+1); MFMA q(1,1)
#pragma unroll
    for (int mi = 0; mi < 2; mi++)
#pragma unroll
      for (int kk = 0; kk < 2; kk++)
        af1[mi][kk] = *(const bf16x8*)(&la[cb][(128 + wr*32 + mi*16 + c15)*64 + (((kk*4 + hi) ^ l7) * 8)]);
    if (t + 1 < NT) STA(nb, 1, t + 1);
    __builtin_amdgcn_s_setprio(1);
#pragma unroll
    for (int mi = 0; mi < 2; mi++)
#pragma unroll
      for (int ni = 0; ni < 2; ni++)
#pragma unroll
        for (int kk = 0; kk < 2; kk++)
          acc[2 + mi][2 + ni] = mfma16(af1[mi][kk], bf1[ni][kk], acc[2 + mi][2 + ni]);
    __builtin_amdgcn_s_setprio(0);

    // ---- P3: MFMA q(1,0)  (bf0 kept live)
    __builtin_amdgcn_s_setprio(1);
#pragma unroll
    for (int mi = 0; mi < 2; mi++)
#pragma unroll
      for (int ni = 0; ni < 2; ni++)
#pragma unroll
        for (int kk = 0; kk < 2; kk++)
          acc[2 + mi][ni] = mfma16(af1[mi][kk], bf0[ni][kk], acc[2 + mi][ni]);
    __builtin_amdgcn_s_setprio(0);
  }
#undef STA
#undef STB

  // ---- epilogue: bias + scatter (Q scaled; V transposed)
#pragma unroll
  for (int mi = 0; mi < 4; mi++) {
    int rbase = m0 + ((mi < 2) ? (wr*32 + mi*16) : (128 + wr*32 + (mi - 2)*16)) + hi*4;
#pragma unroll
    for (int ni = 0; ni < 4; ni++) {
      int n  = n0 + wc*64 + ni*16 + c15;
      int cz = n & 1023;
      float bvv = bias[cz];
      int h = cz >> 6, d = cz & 63;
      int b = rbase >> 11, s = rbase & 2047;
      if (z < 2) {
        bf16* C = z ? Kb : Qb;
        float sc = z ? 1.0f : QSCALE;
#pragma unroll
        for (int r = 0; r < 4; r++)
          C[((b*NH + h)*SEQ + (s + r))*HD + d] = (bf16)((acc[mi][ni][r] + bvv) * sc);
      } else {
        bf16x4 o;
#pragma unroll
        for (int r = 0; r < 4; r++) o[r] = (bf16)(acc[mi][ni][r] + bvv);
        *(bf16x4*)(Vtb + ((size_t)(b*NH + h)*HD + d)*SEQ + s) = o;
      }
    }
  }
}

// Flash attention v5 (round-7 best, verbatim)
__global__ __launch_bounds__(256, 2) void attn(
    const bf16* __restrict__ Q, const bf16* __restrict__ Kin,
    const bf16* __restrict__ Vt, bf16* __restrict__ ctx)
{
  __shared__ __align__(16) bf16 kt[2][128*64];
  __shared__ __align__(16) bf16 vt[2][64*128];

  int tid = threadIdx.x, wid = tid >> 6, lane = tid & 63;
  int l31 = lane & 31, hi = lane >> 5, l7 = lane & 7;

  int orig = blockIdx.y * gridDim.x + blockIdx.x;
  int swz  = (orig & 7) * 64 + (orig >> 3);
  int bh   = swz >> 3, q0 = (swz & 7) * 256;

  const bf16* Qp = Q   + (size_t)bh*SEQ*HD;
  const bf16* Kp = Kin + (size_t)bh*SEQ*HD;
  const bf16* Vp = Vt  + (size_t)bh*HD*SEQ;
  int qw = q0 + wid*64;

  bf16x8 qf[2][4];
#pragma unroll
  for (int qt = 0; qt < 2; qt++)
#pragma unroll
    for (int dblk = 0; dblk < 4; dblk++)
      qf[qt][dblk] = *(const bf16x8*)(Qp + (size_t)(qw + qt*32 + l31)*HD + dblk*16 + hi*8);

  f32x16 po[2][2]  = {};
  f32x16 posum[2]  = {};

  bf16x8 onesv;
#pragma unroll
  for (int j = 0; j < 8; j++) onesv[j] = (bf16)1.0f;

  int r8 = lane >> 3;
  int ck = (lane & 7) ^ r8;
  int r16 = lane >> 4, c16v = lane & 15;

#define STAGE(buf, kv0)                                                        \
  {                                                                            \
    _Pragma("unroll")                                                          \
    for (int op = 0; op < 4; op++) {                                           \
      int rk = wid*32 + op*8 + r8;                                             \
      gload16(&kt[buf][(wid*32 + op*8)*64],                                    \
              Kp + (size_t)((kv0) + rk)*HD + ck*8);                            \
      int rv = wid*16 + op*4 + r16;                                            \
      gload16(&vt[buf][(wid*16 + op*4)*128],                                   \
              Vp + (size_t)rv*SEQ + (kv0) + ((c16v ^ (rv & 7))*8));            \
    }                                                                          \
  }

  STAGE(0, 0);
  __syncthreads();

  for (int it = 0; it < SEQ/128; ++it) {
    int cur = it & 1;
    if (it < SEQ/128 - 1) STAGE(cur ^ 1, (it + 1) * 128);

#pragma unroll
    for (int sub = 0; sub < 2; sub++) {
      f32x16 st[2][2] = {};
      __builtin_amdgcn_s_setprio(1);
#pragma unroll
      for (int kvt = 0; kvt < 2; kvt++) {
        int rowb = (sub*64 + kvt*32 + l31) * 64;
#pragma unroll
        for (int dblk = 0; dblk < 4; dblk++) {
          bf16x8 kf = *(const bf16x8*)(&kt[cur][rowb + (((dblk*2 + hi) ^ l7) * 8)]);
          st[0][kvt] = mfma32(kf, qf[0][dblk], st[0][kvt]);
          st[1][kvt] = mfma32(kf, qf[1][dblk], st[1][kvt]);
        }
      }
      __builtin_amdgcn_s_setprio(0);

      bf16x8 pa[2][2][2];
#pragma unroll
      for (int qt = 0; qt < 2; qt++) {
#pragma unroll
        for (int kvt = 0; kvt < 2; kvt++)
#pragma unroll
          for (int i = 0; i < 16; i++)
            st[qt][kvt][i] = exp2a(st[qt][kvt][i]);
#pragma unroll
        for (int kvt = 0; kvt < 2; kvt++)
#pragma unroll
          for (int cp = 0; cp < 2; cp++) {
            int m0 = 2*cp, m1 = 2*cp + 1;
            unsigned w0a = cvtpk(st[qt][kvt][4*m0+0], st[qt][kvt][4*m0+1]);
            unsigned w1a = cvtpk(st[qt][kvt][4*m0+2], st[qt][kvt][4*m0+3]);
            unsigned w0b = cvtpk(st[qt][kvt][4*m1+0], st[qt][kvt][4*m1+1]);
            unsigned w1b = cvtpk(st[qt][kvt][4*m1+2], st[qt][kvt][4*m1+3]);
            asm("v_permlane32_swap_b32 %0, %1" : "+v"(w0a), "+v"(w0b));
            asm("v_permlane32_swap_b32 %0, %1" : "+v"(w1a), "+v"(w1b));
            pa[qt][kvt][cp] = __builtin_bit_cast(bf16x8, (u32x4v){w0a, w1a, w0b, w1b});
          }
      }

      __builtin_amdgcn_s_setprio(1);
#pragma unroll
      for (int dt = 0; dt < 2; dt++) {
        int rowb = (dt*32 + l31) * 128;
#pragma unroll
        for (int c = 0; c < 4; c++) {
          bf16x8 vf = *(const bf16x8*)(&vt[cur][rowb + ((sub*8 + ((c*2 + hi) ^ l7)) * 8)]);
          po[0][dt] = mfma32(pa[0][c >> 1][c & 1], vf, po[0][dt]);
          po[1][dt] = mfma32(pa[1][c >> 1][c & 1], vf, po[1][dt]);
        }
      }
#pragma unroll
      for (int c = 0; c < 4; c++) {
        posum[0] = mfma32(pa[0][c >> 1][c & 1], onesv, posum[0]);
        posum[1] = mfma32(pa[1][c >> 1][c & 1], onesv, posum[1]);
      }
      __builtin_amdgcn_s_setprio(0);
    }

    __syncthreads();
  }
#undef STAGE

  int b = bh >> 4, h = bh & 15;
#pragma unroll
  for (int qt = 0; qt < 2; qt++)
#pragma unroll
    for (int reg = 0; reg < 16; reg++) {
      int qq = (reg & 3) + 8*(reg >> 2) + 4*hi;
      float inv = 1.0f / posum[qt][reg];
      int s = qw + qt*32 + qq;
      bf16* dst = ctx + (size_t)(b*SEQ + s)*DM + h*HD + l31;
      dst[0]  = (bf16)(po[qt][0][reg] * inv);
      dst[32] = (bf16)(po[qt][1][reg] * inv);
    }
}

extern "C" void kernel_launch(void* const* d_in, const int* in_sizes, int n_in,
                              void* d_out, int out_size, void* d_ws, size_t ws_size,
                              hipStream_t stream)
{
  const float* x  = (const float*)d_in[0];
  const float* Wq = (const float*)d_in[1];
  const float* bq = (const float*)d_in[2];
  const float* Wk = (const float*)d_in[3];
  const float* bk = (const float*)d_in[4];
  const float* Wv = (const float*)d_in[5];
  const float* bv = (const float*)d_in[6];
  const float* Wo = (const float*)d_in[7];
  const float* bo = (const float*)d_in[8];

  bf16* ws  = (bf16*)d_ws;
  bf16* xb  = ws;                          // [8192][1024] bf16 x
  bf16* Wb  = ws + ELEMS;                  // 4 x [1024][1024] bf16 weights (q,k,v,o)
  bf16* Qb  = ws + ELEMS + 4*WELEMS;       // [B,H,S,hd] (pre-scaled)
  bf16* Kb  = Qb + ELEMS;
  bf16* Vtb = Kb + ELEMS;                  // [B,H,hd,S]
  bf16* ctx = xb;                          // reuse x slot (dead after projections)

  cvt_all<<<dim3(ELEMS/1024, 5), dim3(256), 0, stream>>>(x, xb, Wq, Wk, Wv, Wo, Wb);
  gemm_qkv256<<<dim3(768), dim3(512), 0, stream>>>(
      xb, Wb, bq, bk, bv, Qb, Kb, Vtb);
  attn<<<dim3(SEQ/256, BHN), dim3(256), 0, stream>>>(Qb, Kb, Vtb, ctx);
  gemm_out<<<dim3(DM/128, MTOT/128), dim3(256), 0, stream>>>(
      ctx, Wb + 3*WELEMS, bo, (float*)d_out);
}